// Round 8
// baseline (296.142 us; speedup 1.0000x reference)
//
#include <hip/hip_runtime.h>

#pragma clang fp contract(off)

#define BATCH 16
#define NPTS  4096
#define KNN   32
#define NW    8                 // waves per block = candidate-chunk split factor
#define CHUNK (NPTS / NW)       // 512 candidates per wave
#define CH    30
#define Q4    4                 // per-chunk list depth (union 8*4 = 32 -> t_cap bound)
#define FD    32                // per-(wave,lane) index-FIFO depth (u16 entries)
#define FSTR  66                // lane stride per slot-row (bank-conflict-free padding)

#define INF_F __builtin_inff()

// Order-preserving float->uint encoding for atomic max (handles negatives).
__device__ __forceinline__ unsigned enc_f32(float f) {
    unsigned u = __float_as_uint(f);
    return (u & 0x80000000u) ? ~u : (u | 0x80000000u);
}
__device__ __forceinline__ float dec_f32(unsigned e) {
    unsigned u = (e & 0x80000000u) ? (e & 0x7FFFFFFFu) : ~e;
    return __uint_as_float(u);
}

__device__ __forceinline__ float med3f(float a, float b, float c) {
#if __has_builtin(__builtin_amdgcn_fmed3f)
    return __builtin_amdgcn_fmed3f(a, b, c);
#else
    float r;
    asm("v_med3_f32 %0, %1, %2, %3" : "=v"(r) : "v"(a), "v"(b), "v"(c));
    return r;
#endif
}

// Difference-form squared distance, fma-fixed: 6 VALU, no |p|^2 precompute.
// ONE formula used in EVERY pass -> bit-identical d everywhere.
__device__ __forceinline__ float dist3d(float qx, float qy, float qz,
                                        float px, float py, float pz) {
    float r0 = px - qx, r1 = py - qy, r2 = pz - qz;
    return __builtin_fmaf(r0, r0, __builtin_fmaf(r1, r1, r2 * r2));
}

__global__ void init_pool_kernel(unsigned* __restrict__ pool) {
    int i = blockIdx.x * blockDim.x + threadIdx.x;
    if (i < BATCH * CH) pool[i] = 0u;   // 0 is below every encoded finite float
}

// Block: 512 threads = 8 waves. Lane l owns query (qg*64 + l); wave w scans
// candidate chunk [w*512, w*512+512) straight from global (wave-uniform
// addresses -> broadcast L2 lines). ~37 KB LDS -> 4 blocks/CU, 32 waves/CU.
__launch_bounds__(512, 8)
__global__ void knn_feat_kernel(const float* __restrict__ x,
                                unsigned* __restrict__ pool) {
    __shared__ float          t8[NW * 64];                  // 2 KB
    __shared__ unsigned short fifo[NW * (FD + 1) * FSTR];   // 34.8 KB (incl. trash slot)
    __shared__ unsigned char  cbs[NW * 64];                 // 512 B

    const int b   = blockIdx.x >> 6;               // 64 query-groups per batch
    const int qg  = blockIdx.x & 63;
    const int tid = threadIdx.x;
    const int w   = tid >> 6;                      // wave id = chunk id (0..7)
    const int l   = tid & 63;                      // lane = query slot
    const int q   = qg * 64 + l;
    const float* __restrict__ xb = x + (size_t)b * NPTS * 3;

    const float qx = xb[q * 3 + 0], qy = xb[q * 3 + 1], qz = xb[q * 3 + 2];

    const float4* __restrict__ g4 = (const float4*)xb + (size_t)w * (CHUNK * 3 / 4);

    // ---- Pass 1: top-4 distance VALUES of my chunk (sorted asc). ----
    float arr[Q4];
#pragma unroll
    for (int j = 0; j < Q4; ++j) arr[j] = INF_F;

#define INSERT4(dv)                                            \
    {                                                          \
        _Pragma("unroll")                                      \
        for (int j = Q4 - 1; j >= 1; --j)                      \
            arr[j] = med3f(arr[j - 1], arr[j], (dv));          \
        arr[0] = fminf(arr[0], (dv));                          \
    }

#pragma unroll 2
    for (int m4 = 0; m4 < CHUNK / 4; ++m4) {
        float4 A = g4[3 * m4], B = g4[3 * m4 + 1], C = g4[3 * m4 + 2];
        float d0 = dist3d(qx, qy, qz, A.x, A.y, A.z);
        float d1 = dist3d(qx, qy, qz, A.w, B.x, B.y);
        float d2 = dist3d(qx, qy, qz, B.z, B.w, C.x);
        float d3 = dist3d(qx, qy, qz, C.y, C.z, C.w);
        INSERT4(d0); INSERT4(d1); INSERT4(d2); INSERT4(d3);
    }
#undef INSERT4

    t8[w * 64 + l] = arr[Q4 - 1];
    __syncthreads();

    // t_cap >= true 32nd distance: union of 8 chunk-top-4s = 32 distinct points.
    float t_cap = t8[0 * 64 + l];
#pragma unroll
    for (int ww = 1; ww < NW; ++ww) t_cap = fmaxf(t_cap, t8[ww * 64 + l]);

    // ---- Pass 2: branchless collect of chunk-local indices with d <= t_cap.
    // Private lane column, stride FSTR -> bank = (slot + l/2) % 32 (spread).
    unsigned short* __restrict__ fw = fifo + (w * (FD + 1)) * FSTR + l;
    int cnt = 0;
#pragma unroll 2
    for (int m4 = 0; m4 < CHUNK / 4; ++m4) {
        float4 A = g4[3 * m4], B = g4[3 * m4 + 1], C = g4[3 * m4 + 2];
        float d0 = dist3d(qx, qy, qz, A.x, A.y, A.z);
        float d1 = dist3d(qx, qy, qz, A.w, B.x, B.y);
        float d2 = dist3d(qx, qy, qz, B.z, B.w, C.x);
        float d3 = dist3d(qx, qy, qz, C.y, C.z, C.w);
        int mb = m4 * 4;
        {
            bool t = (d0 <= t_cap) && (cnt < FD);
            fw[(t ? cnt : FD) * FSTR] = (unsigned short)(mb + 0);  cnt += t;
        }
        {
            bool t = (d1 <= t_cap) && (cnt < FD);
            fw[(t ? cnt : FD) * FSTR] = (unsigned short)(mb + 1);  cnt += t;
        }
        {
            bool t = (d2 <= t_cap) && (cnt < FD);
            fw[(t ? cnt : FD) * FSTR] = (unsigned short)(mb + 2);  cnt += t;
        }
        {
            bool t = (d3 <= t_cap) && (cnt < FD);
            fw[(t ? cnt : FD) * FSTR] = (unsigned short)(mb + 3);  cnt += t;
        }
    }
    cbs[w * 64 + l] = (unsigned char)cnt;
    __syncthreads();

    if (w != 0) return;   // no barriers past this point

    // ---- Phase 3 (wave 0): exact selection + stats over collected entries.
    // Branchless: wave-uniform bounds; inactive lanes read self (OOB-safe)
    // and get d = INF (falls through the med3 insert as a no-op).
    int cc[NW];
#pragma unroll
    for (int ww = 0; ww < NW; ++ww) cc[ww] = cbs[ww * 64 + l];
    int mc[NW];
#pragma unroll
    for (int ww = 0; ww < NW; ++ww) {
        int m = cc[ww];
#pragma unroll
        for (int off = 32; off >= 1; off >>= 1) {
            int o = __shfl_xor(m, off, 64);
            m = (o > m) ? o : m;
        }
        mc[ww] = m;
    }

    float a32[KNN];
#pragma unroll
    for (int j = 0; j < KNN; ++j) a32[j] = INF_F;

#pragma unroll
    for (int ww = 0; ww < NW; ++ww) {
        const unsigned short* __restrict__ fwp = fifo + (ww * (FD + 1)) * FSTR + l;
        const int c = cc[ww];
        for (int i = 0; i < mc[ww]; ++i) {
            bool act = i < c;
            int idx = act ? ((int)fwp[i * FSTR] + ww * CHUNK) : q;
            const float* pp = xb + 3 * idx;
            float d = dist3d(qx, qy, qz, pp[0], pp[1], pp[2]);
            d = act ? d : INF_F;
#pragma unroll
            for (int j = KNN - 1; j >= 1; --j)
                a32[j] = med3f(a32[j - 1], a32[j], d);
            a32[0] = fminf(a32[0], d);
        }
    }
    const float thr = a32[KNN - 1];
    int c_lt = 0;
#pragma unroll
    for (int j = 0; j < KNN; ++j) c_lt += a32[j] < thr;
    const int need = KNN - c_lt;                   // ties to take, in index order

    float s0 = 0.f, s1 = 0.f, s2 = 0.f;
    float ss0 = 0.f, ss1 = 0.f, ss2 = 0.f;
    float mx0 = -INF_F, mx1 = -INF_F, mx2 = -INF_F;
    float mn0 =  INF_F, mn1 =  INF_F, mn2 =  INF_F;
    int eq_seen = 0;
#pragma unroll
    for (int ww = 0; ww < NW; ++ww) {              // (ww asc, i asc) = index order
        const unsigned short* __restrict__ fwp = fifo + (ww * (FD + 1)) * FSTR + l;
        const int c = cc[ww];
        for (int i = 0; i < mc[ww]; ++i) {
            bool act = i < c;
            int idx = act ? ((int)fwp[i * FSTR] + ww * CHUNK) : q;
            const float* pp = xb + 3 * idx;
            float px = pp[0], py = pp[1], pz = pp[2];
            float d = dist3d(qx, qy, qz, px, py, pz);
            d = act ? d : INF_F;                    // INF: is_eq/take auto-false
            bool is_eq = (d == thr);
            bool take = (d < thr) || (is_eq && eq_seen < need);
            eq_seen += is_eq ? 1 : 0;
            if (take) {
                float r0 = px - qx, r1 = py - qy, r2 = pz - qz;
                s0 += r0;  s1 += r1;  s2 += r2;
                ss0 += r0 * r0;  ss1 += r1 * r1;  ss2 += r2 * r2;
                mx0 = fmaxf(mx0, r0); mx1 = fmaxf(mx1, r1); mx2 = fmaxf(mx2, r2);
                mn0 = fminf(mn0, r0); mn1 = fminf(mn1, r1); mn2 = fminf(mn2, r2);
            }
        }
    }

    const float invk = 1.0f / (float)KNN;
    float mu0 = s0 * invk, mu1 = s1 * invk, mu2 = s2 * invk;
    float ex0 = ss0 * invk, ex1 = ss1 * invk, ex2 = ss2 * invk;
    float st0 = sqrtf(fmaxf(ex0 - mu0 * mu0, 0.f));
    float st1 = sqrtf(fmaxf(ex1 - mu1 * mu1, 0.f));
    float st2 = sqrtf(fmaxf(ex2 - mu2 * mu2, 0.f));
    float nrm = sqrtf(mu0 * mu0 + mu1 * mu1 + mu2 * mu2) + 1e-8f;
    float u0 = mu0 / nrm, u1 = mu1 / nrm, u2 = mu2 / nrm;
    float cr0 = qy * u2 - qz * u1;
    float cr1 = qz * u0 - qx * u2;
    float cr2 = qx * u1 - qy * u0;
    float mq0 = fmaxf(mx0 * mx0, mn0 * mn0);
    float mq1 = fmaxf(mx1 * mx1, mn1 * mn1);
    float mq2 = fmaxf(mx2 * mx2, mn2 * mn2);

    float f[CH] = { qx, qy, qz,
                    mu0, mu1, mu2,
                    mx0, mx1, mx2,
                    mn0, mn1, mn2,
                    st0, st1, st2,
                    qx - mu0, qy - mu1, qz - mu2,
                    u0, u1, u2,
                    cr0, cr1, cr2,
                    mq0, mq1, mq2,
                    ex0, ex1, ex2 };

#pragma unroll
    for (int c = 0; c < CH; ++c) {
        float v = f[c];
#pragma unroll
        for (int off = 32; off >= 1; off >>= 1)
            v = fmaxf(v, __shfl_xor(v, off, 64));
        if (l == 0)
            atomicMax(pool + b * CH + c, enc_f32(v));
    }
}

__global__ void final_mm_kernel(const unsigned* __restrict__ pool,
                                const float* __restrict__ W,
                                const float* __restrict__ bias,
                                float* __restrict__ out) {
    int t = blockIdx.x * blockDim.x + threadIdx.x;
    if (t >= BATCH * 32) return;
    int bb = t >> 5, e = t & 31;
    float acc = bias[e];
#pragma unroll
    for (int c = 0; c < CH; ++c)
        acc += dec_f32(pool[bb * CH + c]) * W[e * CH + c];
    out[bb * 32 + e] = acc;
}

extern "C" void kernel_launch(void* const* d_in, const int* in_sizes, int n_in,
                              void* d_out, int out_size, void* d_ws, size_t ws_size,
                              hipStream_t stream) {
    const float* x    = (const float*)d_in[0];   // [16, 4096, 3] f32
    const float* W    = (const float*)d_in[1];   // [32, 30] f32
    const float* bias = (const float*)d_in[2];   // [32] f32
    float*       out  = (float*)d_out;           // [16, 32] f32
    unsigned*    pool = (unsigned*)d_ws;         // [16, 30] encoded f32

    hipLaunchKernelGGL(init_pool_kernel, dim3(1), dim3(512), 0, stream, pool);
    hipLaunchKernelGGL(knn_feat_kernel, dim3(BATCH * (NPTS / 64)), dim3(512),
                       0, stream, x, pool);
    hipLaunchKernelGGL(final_mm_kernel, dim3(1), dim3(512), 0, stream, pool, W, bias, out);
}

// Round 9
// 291.300 us; speedup vs baseline: 1.0166x; 1.0166x over previous
//
#include <hip/hip_runtime.h>

#pragma clang fp contract(off)

#define BATCH 16
#define NPTS  4096
#define KNN   32
#define CH    30

// Kernel A (bound): 8 waves, chunk 512, top-4 per chunk (union 8*4=32 -> bound)
#define NWA     8
#define CHUNKA  (NPTS / NWA)     // 512
#define QA      4
// Kernel B (collect+select): 4 waves, chunk 1024, FIFO of d<=t_cap survivors
#define NWB     4
#define CHUNKB  (NPTS / NWB)     // 1024
#define FD      48               // per-(wave,lane) FIFO depth; slot FD = trash

#define INF_F __builtin_inff()

// Order-preserving float->uint encoding for atomic max (handles negatives).
__device__ __forceinline__ unsigned enc_f32(float f) {
    unsigned u = __float_as_uint(f);
    return (u & 0x80000000u) ? ~u : (u | 0x80000000u);
}
__device__ __forceinline__ float dec_f32(unsigned e) {
    unsigned u = (e & 0x80000000u) ? (e & 0x7FFFFFFFu) : ~e;
    return __uint_as_float(u);
}

__device__ __forceinline__ float med3f(float a, float b, float c) {
#if __has_builtin(__builtin_amdgcn_fmed3f)
    return __builtin_amdgcn_fmed3f(a, b, c);
#else
    float r;
    asm("v_med3_f32 %0, %1, %2, %3" : "=v"(r) : "v"(a), "v"(b), "v"(c));
    return r;
#endif
}

// Difference-form squared distance, fma-fixed: 6 VALU. ONE formula used in
// EVERY pass of BOTH kernels -> bit-identical d everywhere (contract off).
__device__ __forceinline__ float dist3d(float qx, float qy, float qz,
                                        float px, float py, float pz) {
    float r0 = px - qx, r1 = py - qy, r2 = pz - qz;
    return __builtin_fmaf(r0, r0, __builtin_fmaf(r1, r1, r2 * r2));
}

__global__ void init_pool_kernel(unsigned* __restrict__ pool) {
    int i = blockIdx.x * blockDim.x + threadIdx.x;
    if (i < BATCH * CH) pool[i] = 0u;   // 0 is below every encoded finite float
}

// ---- Kernel A: per-query upper bound t_cap on the 32nd-smallest distance.
// 512 thr = 8 waves; wave w keeps top-4 of chunk [w*512, w*512+512) per lane
// query. Union of 8 top-4 lists = 32 distinct points => max of the 8 arr[3]
// values >= true d32. Tiny LDS (2 KB) -> 4 blocks/CU, 32 waves/CU.
__launch_bounds__(512, 8)
__global__ void knn_bound_kernel(const float* __restrict__ x,
                                 float* __restrict__ tcap) {
    __shared__ float t8[NWA * 64];                 // 2 KB

    const int b   = blockIdx.x >> 6;               // 64 query-groups per batch
    const int qg  = blockIdx.x & 63;
    const int tid = threadIdx.x;
    const int w   = tid >> 6;                      // wave id = chunk id (0..7)
    const int l   = tid & 63;                      // lane = query slot
    const int q   = qg * 64 + l;
    const float* __restrict__ xb = x + (size_t)b * NPTS * 3;

    const float qx = xb[q * 3 + 0], qy = xb[q * 3 + 1], qz = xb[q * 3 + 2];
    const float4* __restrict__ g4 = (const float4*)xb + (size_t)w * (CHUNKA * 3 / 4);

    float arr[QA];
#pragma unroll
    for (int j = 0; j < QA; ++j) arr[j] = INF_F;

#define INSERT4(dv)                                            \
    {                                                          \
        _Pragma("unroll")                                      \
        for (int j = QA - 1; j >= 1; --j)                      \
            arr[j] = med3f(arr[j - 1], arr[j], (dv));          \
        arr[0] = fminf(arr[0], (dv));                          \
    }

#pragma unroll 2
    for (int m4 = 0; m4 < CHUNKA / 4; ++m4) {
        float4 A = g4[3 * m4], B = g4[3 * m4 + 1], C = g4[3 * m4 + 2];
        float d0 = dist3d(qx, qy, qz, A.x, A.y, A.z);
        float d1 = dist3d(qx, qy, qz, A.w, B.x, B.y);
        float d2 = dist3d(qx, qy, qz, B.z, B.w, C.x);
        float d3 = dist3d(qx, qy, qz, C.y, C.z, C.w);
        INSERT4(d0); INSERT4(d1); INSERT4(d2); INSERT4(d3);
    }
#undef INSERT4

    t8[w * 64 + l] = arr[QA - 1];
    __syncthreads();

    if (w == 0) {
        float t = t8[l];
#pragma unroll
        for (int ww = 1; ww < NWA; ++ww) t = fmaxf(t, t8[ww * 64 + l]);
        tcap[(size_t)b * NPTS + q] = t;
    }
}

// ---- Kernel B: collect survivors (d <= t_cap) then exact top-32 + stats.
// 256 thr = 4 waves, chunk 1024/wave; 128 VGPR budget (no a32 spill).
__launch_bounds__(256, 4)
__global__ void knn_feat_kernel(const float* __restrict__ x,
                                const float* __restrict__ tcap,
                                unsigned* __restrict__ pool) {
    __shared__ unsigned short fifo[NWB * (FD + 1) * 64];   // 25 KB (incl. trash)
    __shared__ unsigned char  cbs[NWB * 64];               // 256 B

    const int b   = blockIdx.x >> 6;
    const int qg  = blockIdx.x & 63;
    const int tid = threadIdx.x;
    const int w   = tid >> 6;                      // wave id = chunk id (0..3)
    const int l   = tid & 63;
    const int q   = qg * 64 + l;
    const float* __restrict__ xb = x + (size_t)b * NPTS * 3;

    const float qx = xb[q * 3 + 0], qy = xb[q * 3 + 1], qz = xb[q * 3 + 2];
    const float t_cap = tcap[(size_t)b * NPTS + q];

    const float4* __restrict__ g4 = (const float4*)xb + (size_t)w * (CHUNKB * 3 / 4);

    // Pass 2: branchless collect of chunk-local indices with d <= t_cap.
    // Lane column stride 64 u16: byte = base + (slot<<7) + 2l -> bank = l>>1
    // (pure 2-lane pairing, free); slot addr = one lshl_add.
    unsigned short* __restrict__ fw = fifo + (w * (FD + 1)) * 64 + l;
    int cnt = 0;
#pragma unroll 2
    for (int m4 = 0; m4 < CHUNKB / 4; ++m4) {
        float4 A = g4[3 * m4], B = g4[3 * m4 + 1], C = g4[3 * m4 + 2];
        float d0 = dist3d(qx, qy, qz, A.x, A.y, A.z);
        float d1 = dist3d(qx, qy, qz, A.w, B.x, B.y);
        float d2 = dist3d(qx, qy, qz, B.z, B.w, C.x);
        float d3 = dist3d(qx, qy, qz, C.y, C.z, C.w);
        int mb = m4 * 4;
        {
            bool t = (d0 <= t_cap) && (cnt < FD);
            fw[(t ? cnt : FD) * 64] = (unsigned short)(mb + 0);  cnt += t;
        }
        {
            bool t = (d1 <= t_cap) && (cnt < FD);
            fw[(t ? cnt : FD) * 64] = (unsigned short)(mb + 1);  cnt += t;
        }
        {
            bool t = (d2 <= t_cap) && (cnt < FD);
            fw[(t ? cnt : FD) * 64] = (unsigned short)(mb + 2);  cnt += t;
        }
        {
            bool t = (d3 <= t_cap) && (cnt < FD);
            fw[(t ? cnt : FD) * 64] = (unsigned short)(mb + 3);  cnt += t;
        }
    }
    cbs[w * 64 + l] = (unsigned char)cnt;
    __syncthreads();

    if (w != 0) return;   // no barriers past this point

    // Phase 3 (wave 0): exact selection + stats. Branchless: wave-uniform
    // bounds; inactive lanes get d = INF (no-op through the med3 insert).
    int cc[NWB];
#pragma unroll
    for (int ww = 0; ww < NWB; ++ww) cc[ww] = cbs[ww * 64 + l];
    int mc[NWB];
#pragma unroll
    for (int ww = 0; ww < NWB; ++ww) {
        int m = cc[ww];
#pragma unroll
        for (int off = 32; off >= 1; off >>= 1) {
            int o = __shfl_xor(m, off, 64);
            m = (o > m) ? o : m;
        }
        mc[ww] = m;
    }

    float a32[KNN];
#pragma unroll
    for (int j = 0; j < KNN; ++j) a32[j] = INF_F;

#pragma unroll
    for (int ww = 0; ww < NWB; ++ww) {
        const unsigned short* __restrict__ fwp = fifo + (ww * (FD + 1)) * 64 + l;
        const int c = cc[ww];
        for (int i = 0; i < mc[ww]; ++i) {
            bool act = i < c;
            int idx = act ? ((int)fwp[i * 64] + ww * CHUNKB) : q;
            const float* pp = xb + 3 * idx;
            float d = dist3d(qx, qy, qz, pp[0], pp[1], pp[2]);
            d = act ? d : INF_F;
#pragma unroll
            for (int j = KNN - 1; j >= 1; --j)
                a32[j] = med3f(a32[j - 1], a32[j], d);
            a32[0] = fminf(a32[0], d);
        }
    }
    const float thr = a32[KNN - 1];
    int c_lt = 0;
#pragma unroll
    for (int j = 0; j < KNN; ++j) c_lt += a32[j] < thr;
    const int need = KNN - c_lt;                   // ties to take, in index order

    float s0 = 0.f, s1 = 0.f, s2 = 0.f;
    float ss0 = 0.f, ss1 = 0.f, ss2 = 0.f;
    float mx0 = -INF_F, mx1 = -INF_F, mx2 = -INF_F;
    float mn0 =  INF_F, mn1 =  INF_F, mn2 =  INF_F;
    int eq_seen = 0;
#pragma unroll
    for (int ww = 0; ww < NWB; ++ww) {             // (ww asc, i asc) = index order
        const unsigned short* __restrict__ fwp = fifo + (ww * (FD + 1)) * 64 + l;
        const int c = cc[ww];
        for (int i = 0; i < mc[ww]; ++i) {
            bool act = i < c;
            int idx = act ? ((int)fwp[i * 64] + ww * CHUNKB) : q;
            const float* pp = xb + 3 * idx;
            float px = pp[0], py = pp[1], pz = pp[2];
            float d = dist3d(qx, qy, qz, px, py, pz);
            d = act ? d : INF_F;                    // INF: is_eq/take auto-false
            bool is_eq = (d == thr);
            bool take = (d < thr) || (is_eq && eq_seen < need);
            eq_seen += is_eq ? 1 : 0;
            if (take) {
                float r0 = px - qx, r1 = py - qy, r2 = pz - qz;
                s0 += r0;  s1 += r1;  s2 += r2;
                ss0 += r0 * r0;  ss1 += r1 * r1;  ss2 += r2 * r2;
                mx0 = fmaxf(mx0, r0); mx1 = fmaxf(mx1, r1); mx2 = fmaxf(mx2, r2);
                mn0 = fminf(mn0, r0); mn1 = fminf(mn1, r1); mn2 = fminf(mn2, r2);
            }
        }
    }

    const float invk = 1.0f / (float)KNN;
    float mu0 = s0 * invk, mu1 = s1 * invk, mu2 = s2 * invk;
    float ex0 = ss0 * invk, ex1 = ss1 * invk, ex2 = ss2 * invk;
    float st0 = sqrtf(fmaxf(ex0 - mu0 * mu0, 0.f));
    float st1 = sqrtf(fmaxf(ex1 - mu1 * mu1, 0.f));
    float st2 = sqrtf(fmaxf(ex2 - mu2 * mu2, 0.f));
    float nrm = sqrtf(mu0 * mu0 + mu1 * mu1 + mu2 * mu2) + 1e-8f;
    float u0 = mu0 / nrm, u1 = mu1 / nrm, u2 = mu2 / nrm;
    float cr0 = qy * u2 - qz * u1;
    float cr1 = qz * u0 - qx * u2;
    float cr2 = qx * u1 - qy * u0;
    float mq0 = fmaxf(mx0 * mx0, mn0 * mn0);
    float mq1 = fmaxf(mx1 * mx1, mn1 * mn1);
    float mq2 = fmaxf(mx2 * mx2, mn2 * mn2);

    float f[CH] = { qx, qy, qz,
                    mu0, mu1, mu2,
                    mx0, mx1, mx2,
                    mn0, mn1, mn2,
                    st0, st1, st2,
                    qx - mu0, qy - mu1, qz - mu2,
                    u0, u1, u2,
                    cr0, cr1, cr2,
                    mq0, mq1, mq2,
                    ex0, ex1, ex2 };

#pragma unroll
    for (int c = 0; c < CH; ++c) {
        float v = f[c];
#pragma unroll
        for (int off = 32; off >= 1; off >>= 1)
            v = fmaxf(v, __shfl_xor(v, off, 64));
        if (l == 0)
            atomicMax(pool + b * CH + c, enc_f32(v));
    }
}

__global__ void final_mm_kernel(const unsigned* __restrict__ pool,
                                const float* __restrict__ W,
                                const float* __restrict__ bias,
                                float* __restrict__ out) {
    int t = blockIdx.x * blockDim.x + threadIdx.x;
    if (t >= BATCH * 32) return;
    int bb = t >> 5, e = t & 31;
    float acc = bias[e];
#pragma unroll
    for (int c = 0; c < CH; ++c)
        acc += dec_f32(pool[bb * CH + c]) * W[e * CH + c];
    out[bb * 32 + e] = acc;
}

extern "C" void kernel_launch(void* const* d_in, const int* in_sizes, int n_in,
                              void* d_out, int out_size, void* d_ws, size_t ws_size,
                              hipStream_t stream) {
    const float* x    = (const float*)d_in[0];   // [16, 4096, 3] f32
    const float* W    = (const float*)d_in[1];   // [32, 30] f32
    const float* bias = (const float*)d_in[2];   // [32] f32
    float*       out  = (float*)d_out;           // [16, 32] f32

    unsigned* pool = (unsigned*)d_ws;                          // [16,30] @ offset 0
    float*    tcap = (float*)((char*)d_ws + 2048);             // [16,4096] 256 KB

    hipLaunchKernelGGL(init_pool_kernel, dim3(1), dim3(512), 0, stream, pool);
    hipLaunchKernelGGL(knn_bound_kernel, dim3(BATCH * (NPTS / 64)), dim3(512),
                       0, stream, x, tcap);
    hipLaunchKernelGGL(knn_feat_kernel, dim3(BATCH * (NPTS / 64)), dim3(256),
                       0, stream, x, tcap, pool);
    hipLaunchKernelGGL(final_mm_kernel, dim3(1), dim3(512), 0, stream, pool, W, bias, out);
}

// Round 10
// 270.872 us; speedup vs baseline: 1.0933x; 1.0754x over previous
//
#include <hip/hip_runtime.h>

#pragma clang fp contract(off)

#define BATCH 16
#define NPTS  4096
#define KNN   32
#define CH    30

// Kernel A (bound): 8 waves, chunk 512, top-4 per chunk (union 8*4=32 -> bound)
#define NWA     8
#define CHUNKA  (NPTS / NWA)     // 512
#define QA      4
// Kernel B (collect+select): 4 waves, chunk 1024, FIFO of d<=t_cap survivors
#define NWB     4
#define CHUNKB  (NPTS / NWB)     // 1024
#define FD      48               // per-(region,lane) FIFO depth; slot FD = trash
#define FSTRIDE 50               // u16 slots per lane column (>= FD+1, bank-spread)

#define INF_F __builtin_inff()

// Order-preserving float->uint encoding for atomic max (handles negatives).
__device__ __forceinline__ unsigned enc_f32(float f) {
    unsigned u = __float_as_uint(f);
    return (u & 0x80000000u) ? ~u : (u | 0x80000000u);
}
__device__ __forceinline__ float dec_f32(unsigned e) {
    unsigned u = (e & 0x80000000u) ? (e & 0x7FFFFFFFu) : ~e;
    return __uint_as_float(u);
}

__device__ __forceinline__ float med3f(float a, float b, float c) {
#if __has_builtin(__builtin_amdgcn_fmed3f)
    return __builtin_amdgcn_fmed3f(a, b, c);
#else
    float r;
    asm("v_med3_f32 %0, %1, %2, %3" : "=v"(r) : "v"(a), "v"(b), "v"(c));
    return r;
#endif
}

// Difference-form squared distance, fma-fixed: 6 VALU. ONE formula used in
// EVERY pass of BOTH kernels -> bit-identical d everywhere (contract off).
__device__ __forceinline__ float dist3d(float qx, float qy, float qz,
                                        float px, float py, float pz) {
    float r0 = px - qx, r1 = py - qy, r2 = pz - qz;
    return __builtin_fmaf(r0, r0, __builtin_fmaf(r1, r1, r2 * r2));
}

__global__ void init_pool_kernel(unsigned* __restrict__ pool) {
    int i = blockIdx.x * blockDim.x + threadIdx.x;
    if (i < BATCH * CH) pool[i] = 0u;   // 0 is below every encoded finite float
}

// ---- Kernel A: per-query upper bound t_cap on the 32nd-smallest distance.
// Union of 8 chunk-top-4 lists = 32 distinct points => max of the 8 arr[3]
// values >= true d32.
__launch_bounds__(512, 8)
__global__ void knn_bound_kernel(const float* __restrict__ x,
                                 float* __restrict__ tcap) {
    __shared__ float t8[NWA * 64];                 // 2 KB

    const int b   = blockIdx.x >> 6;               // 64 query-groups per batch
    const int qg  = blockIdx.x & 63;
    const int tid = threadIdx.x;
    const int w   = tid >> 6;                      // wave id = chunk id (0..7)
    const int l   = tid & 63;                      // lane = query slot
    const int q   = qg * 64 + l;
    const float* __restrict__ xb = x + (size_t)b * NPTS * 3;

    const float qx = xb[q * 3 + 0], qy = xb[q * 3 + 1], qz = xb[q * 3 + 2];
    const float4* __restrict__ g4 = (const float4*)xb + (size_t)w * (CHUNKA * 3 / 4);

    float arr[QA];
#pragma unroll
    for (int j = 0; j < QA; ++j) arr[j] = INF_F;

#define INSERT4(dv)                                            \
    {                                                          \
        _Pragma("unroll")                                      \
        for (int j = QA - 1; j >= 1; --j)                      \
            arr[j] = med3f(arr[j - 1], arr[j], (dv));          \
        arr[0] = fminf(arr[0], (dv));                          \
    }

#pragma unroll 2
    for (int m4 = 0; m4 < CHUNKA / 4; ++m4) {
        float4 A = g4[3 * m4], B = g4[3 * m4 + 1], C = g4[3 * m4 + 2];
        float d0 = dist3d(qx, qy, qz, A.x, A.y, A.z);
        float d1 = dist3d(qx, qy, qz, A.w, B.x, B.y);
        float d2 = dist3d(qx, qy, qz, B.z, B.w, C.x);
        float d3 = dist3d(qx, qy, qz, C.y, C.z, C.w);
        INSERT4(d0); INSERT4(d1); INSERT4(d2); INSERT4(d3);
    }
#undef INSERT4

    t8[w * 64 + l] = arr[QA - 1];
    __syncthreads();

    if (w == 0) {
        float t = t8[l];
#pragma unroll
        for (int ww = 1; ww < NWA; ++ww) t = fmaxf(t, t8[ww * 64 + l]);
        tcap[(size_t)b * NPTS + q] = t;
    }
}

// ---- Kernel B: collect survivors (d <= t_cap) then exact top-32 + stats.
__launch_bounds__(256, 4)
__global__ void knn_feat_kernel(const float* __restrict__ x,
                                const float* __restrict__ tcap,
                                unsigned* __restrict__ pool) {
    __shared__ unsigned short fifo[NWB * 64 * FSTRIDE];    // 25.0 KB [w][l][slot]
    __shared__ unsigned char  cbs[NWB * 64];               // 256 B

    const int b   = blockIdx.x >> 6;
    const int qg  = blockIdx.x & 63;
    const int tid = threadIdx.x;
    const int w   = tid >> 6;                      // wave id = chunk id (0..3)
    const int l   = tid & 63;
    const int q   = qg * 64 + l;
    const float* __restrict__ xb = x + (size_t)b * NPTS * 3;

    const float qx = xb[q * 3 + 0], qy = xb[q * 3 + 1], qz = xb[q * 3 + 2];
    const float t_cap = tcap[(size_t)b * NPTS + q];

    const float4* __restrict__ g4 = (const float4*)xb + (size_t)w * (CHUNKB * 3 / 4);

    // Pass 2: branchless collect of GLOBAL u16 indices with d <= t_cap.
    // Lane column contiguous (stride 50 u16 = 100 B): write bank = 25*l + s/2
    // mod 32 -> full spread (~2-way pairing = free). Slot FD = trash.
    unsigned short* __restrict__ fl = fifo + (w * 64 + l) * FSTRIDE;
    int cnt = 0;
#pragma unroll 2
    for (int m4 = 0; m4 < CHUNKB / 4; ++m4) {
        float4 A = g4[3 * m4], B = g4[3 * m4 + 1], C = g4[3 * m4 + 2];
        float d0 = dist3d(qx, qy, qz, A.x, A.y, A.z);
        float d1 = dist3d(qx, qy, qz, A.w, B.x, B.y);
        float d2 = dist3d(qx, qy, qz, B.z, B.w, C.x);
        float d3 = dist3d(qx, qy, qz, C.y, C.z, C.w);
        int mb = w * CHUNKB + m4 * 4;              // global candidate index
        {
            bool t = (d0 <= t_cap) && (cnt < FD);
            fl[t ? cnt : FD] = (unsigned short)(mb + 0);  cnt += t;
        }
        {
            bool t = (d1 <= t_cap) && (cnt < FD);
            fl[t ? cnt : FD] = (unsigned short)(mb + 1);  cnt += t;
        }
        {
            bool t = (d2 <= t_cap) && (cnt < FD);
            fl[t ? cnt : FD] = (unsigned short)(mb + 2);  cnt += t;
        }
        {
            bool t = (d3 <= t_cap) && (cnt < FD);
            fl[t ? cnt : FD] = (unsigned short)(mb + 3);  cnt += t;
        }
    }
    cbs[w * 64 + l] = (unsigned char)cnt;
    __syncthreads();

    if (w != 0) return;   // no barriers past this point

    // ---- Phase 3 (wave 0): software-pipelined exact selection + stats.
    int cc[NWB], mc[NWB];
#pragma unroll
    for (int ww = 0; ww < NWB; ++ww) {
        int c = cbs[ww * 64 + l];
        cc[ww] = c;
        int m = c;
#pragma unroll
        for (int off = 32; off >= 1; off >>= 1) {
            int o = __shfl_xor(m, off, 64);
            m = (o > m) ? o : m;
        }
        mc[ww] = m;
    }

    // Load 4 survivor coords for group g_ of region-lane FIFO flp.
    // Garbage slots masked to [0,4095] (in-bounds read), gated by act later.
#define LOADG(flp, g_, X0, Y0, Z0, X1, Y1, Z1, X2, Y2, Z2, X3, Y3, Z3)        \
    {                                                                         \
        const unsigned* p32_ = (const unsigned*)((flp) + (g_) * 4);           \
        unsigned v0_ = p32_[0], v1_ = p32_[1];                                \
        int i0_ = (int)(v0_ & 0xFFFu);                                        \
        int i1_ = (int)((v0_ >> 16) & 0xFFFu);                                \
        int i2_ = (int)(v1_ & 0xFFFu);                                        \
        int i3_ = (int)((v1_ >> 16) & 0xFFFu);                                \
        const float* p0_ = xb + 3 * i0_;                                      \
        const float* p1_ = xb + 3 * i1_;                                      \
        const float* p2_ = xb + 3 * i2_;                                      \
        const float* p3_ = xb + 3 * i3_;                                      \
        X0 = p0_[0]; Y0 = p0_[1]; Z0 = p0_[2];                                \
        X1 = p1_[0]; Y1 = p1_[1]; Z1 = p1_[2];                                \
        X2 = p2_[0]; Y2 = p2_[1]; Z2 = p2_[2];                                \
        X3 = p3_[0]; Y3 = p3_[1]; Z3 = p3_[2];                                \
    }

    // ---- Select pass: exact top-32 over all survivors. ----
    float a32[KNN];
#pragma unroll
    for (int j = 0; j < KNN; ++j) a32[j] = INF_F;

#define INSERT32(dv)                                                          \
    {                                                                         \
        _Pragma("unroll")                                                     \
        for (int j = KNN - 1; j >= 1; --j)                                    \
            a32[j] = med3f(a32[j - 1], a32[j], (dv));                         \
        a32[0] = fminf(a32[0], (dv));                                         \
    }

#pragma unroll
    for (int ww = 0; ww < NWB; ++ww) {
        const unsigned short* flp = fifo + (ww * 64 + l) * FSTRIDE;
        const int c = cc[ww];
        const int grp = (mc[ww] + 3) >> 2;
        if (grp > 0) {
            float cx0, cy0, cz0, cx1, cy1, cz1, cx2, cy2, cz2, cx3, cy3, cz3;
            LOADG(flp, 0, cx0, cy0, cz0, cx1, cy1, cz1, cx2, cy2, cz2, cx3, cy3, cz3);
            for (int g = 0; g < grp; ++g) {
                float nx0, ny0, nz0, nx1, ny1, nz1, nx2, ny2, nz2, nx3, ny3, nz3;
                int gn = (g + 1 < grp) ? (g + 1) : g;   // guarded prefetch
                LOADG(flp, gn, nx0, ny0, nz0, nx1, ny1, nz1, nx2, ny2, nz2, nx3, ny3, nz3);
                float d0 = dist3d(qx, qy, qz, cx0, cy0, cz0);
                float d1 = dist3d(qx, qy, qz, cx1, cy1, cz1);
                float d2 = dist3d(qx, qy, qz, cx2, cy2, cz2);
                float d3 = dist3d(qx, qy, qz, cx3, cy3, cz3);
                int gi = g * 4;
                d0 = (gi + 0 < c) ? d0 : INF_F;
                d1 = (gi + 1 < c) ? d1 : INF_F;
                d2 = (gi + 2 < c) ? d2 : INF_F;
                d3 = (gi + 3 < c) ? d3 : INF_F;
                INSERT32(d0); INSERT32(d1); INSERT32(d2); INSERT32(d3);
                cx0 = nx0; cy0 = ny0; cz0 = nz0;  cx1 = nx1; cy1 = ny1; cz1 = nz1;
                cx2 = nx2; cy2 = ny2; cz2 = nz2;  cx3 = nx3; cy3 = ny3; cz3 = nz3;
            }
        }
    }
#undef INSERT32

    const float thr = a32[KNN - 1];
    int c_lt = 0;
#pragma unroll
    for (int j = 0; j < KNN; ++j) c_lt += a32[j] < thr;
    const int need = KNN - c_lt;                   // ties to take, in index order

    // ---- Stats pass over the same survivors (pipelined identically). ----
    float s0 = 0.f, s1 = 0.f, s2 = 0.f;
    float ss0 = 0.f, ss1 = 0.f, ss2 = 0.f;
    float mx0 = -INF_F, mx1 = -INF_F, mx2 = -INF_F;
    float mn0 =  INF_F, mn1 =  INF_F, mn2 =  INF_F;
    int eq_seen = 0;

#define STAT1(PX, PY, PZ, ACT)                                                \
    {                                                                         \
        float d_ = dist3d(qx, qy, qz, (PX), (PY), (PZ));                      \
        d_ = (ACT) ? d_ : INF_F;                                              \
        bool is_eq_ = (d_ == thr);                                            \
        bool take_ = (d_ < thr) || (is_eq_ && eq_seen < need);                \
        eq_seen += is_eq_ ? 1 : 0;                                            \
        if (take_) {                                                          \
            float r0_ = (PX) - qx, r1_ = (PY) - qy, r2_ = (PZ) - qz;          \
            s0 += r0_;  s1 += r1_;  s2 += r2_;                                \
            ss0 += r0_ * r0_;  ss1 += r1_ * r1_;  ss2 += r2_ * r2_;           \
            mx0 = fmaxf(mx0, r0_); mx1 = fmaxf(mx1, r1_); mx2 = fmaxf(mx2, r2_); \
            mn0 = fminf(mn0, r0_); mn1 = fminf(mn1, r1_); mn2 = fminf(mn2, r2_); \
        }                                                                     \
    }

#pragma unroll
    for (int ww = 0; ww < NWB; ++ww) {             // (ww asc, g asc, k asc) = index order
        const unsigned short* flp = fifo + (ww * 64 + l) * FSTRIDE;
        const int c = cc[ww];
        const int grp = (mc[ww] + 3) >> 2;
        if (grp > 0) {
            float cx0, cy0, cz0, cx1, cy1, cz1, cx2, cy2, cz2, cx3, cy3, cz3;
            LOADG(flp, 0, cx0, cy0, cz0, cx1, cy1, cz1, cx2, cy2, cz2, cx3, cy3, cz3);
            for (int g = 0; g < grp; ++g) {
                float nx0, ny0, nz0, nx1, ny1, nz1, nx2, ny2, nz2, nx3, ny3, nz3;
                int gn = (g + 1 < grp) ? (g + 1) : g;
                LOADG(flp, gn, nx0, ny0, nz0, nx1, ny1, nz1, nx2, ny2, nz2, nx3, ny3, nz3);
                int gi = g * 4;
                STAT1(cx0, cy0, cz0, gi + 0 < c);
                STAT1(cx1, cy1, cz1, gi + 1 < c);
                STAT1(cx2, cy2, cz2, gi + 2 < c);
                STAT1(cx3, cy3, cz3, gi + 3 < c);
                cx0 = nx0; cy0 = ny0; cz0 = nz0;  cx1 = nx1; cy1 = ny1; cz1 = nz1;
                cx2 = nx2; cy2 = ny2; cz2 = nz2;  cx3 = nx3; cy3 = ny3; cz3 = nz3;
            }
        }
    }
#undef STAT1
#undef LOADG

    const float invk = 1.0f / (float)KNN;
    float mu0 = s0 * invk, mu1 = s1 * invk, mu2 = s2 * invk;
    float ex0 = ss0 * invk, ex1 = ss1 * invk, ex2 = ss2 * invk;
    float st0 = sqrtf(fmaxf(ex0 - mu0 * mu0, 0.f));
    float st1 = sqrtf(fmaxf(ex1 - mu1 * mu1, 0.f));
    float st2 = sqrtf(fmaxf(ex2 - mu2 * mu2, 0.f));
    float nrm = sqrtf(mu0 * mu0 + mu1 * mu1 + mu2 * mu2) + 1e-8f;
    float u0 = mu0 / nrm, u1 = mu1 / nrm, u2 = mu2 / nrm;
    float cr0 = qy * u2 - qz * u1;
    float cr1 = qz * u0 - qx * u2;
    float cr2 = qx * u1 - qy * u0;
    float mq0 = fmaxf(mx0 * mx0, mn0 * mn0);
    float mq1 = fmaxf(mx1 * mx1, mn1 * mn1);
    float mq2 = fmaxf(mx2 * mx2, mn2 * mn2);

    float f[CH] = { qx, qy, qz,
                    mu0, mu1, mu2,
                    mx0, mx1, mx2,
                    mn0, mn1, mn2,
                    st0, st1, st2,
                    qx - mu0, qy - mu1, qz - mu2,
                    u0, u1, u2,
                    cr0, cr1, cr2,
                    mq0, mq1, mq2,
                    ex0, ex1, ex2 };

#pragma unroll
    for (int c = 0; c < CH; ++c) {
        float v = f[c];
#pragma unroll
        for (int off = 32; off >= 1; off >>= 1)
            v = fmaxf(v, __shfl_xor(v, off, 64));
        if (l == 0)
            atomicMax(pool + b * CH + c, enc_f32(v));
    }
}

__global__ void final_mm_kernel(const unsigned* __restrict__ pool,
                                const float* __restrict__ W,
                                const float* __restrict__ bias,
                                float* __restrict__ out) {
    int t = blockIdx.x * blockDim.x + threadIdx.x;
    if (t >= BATCH * 32) return;
    int bb = t >> 5, e = t & 31;
    float acc = bias[e];
#pragma unroll
    for (int c = 0; c < CH; ++c)
        acc += dec_f32(pool[bb * CH + c]) * W[e * CH + c];
    out[bb * 32 + e] = acc;
}

extern "C" void kernel_launch(void* const* d_in, const int* in_sizes, int n_in,
                              void* d_out, int out_size, void* d_ws, size_t ws_size,
                              hipStream_t stream) {
    const float* x    = (const float*)d_in[0];   // [16, 4096, 3] f32
    const float* W    = (const float*)d_in[1];   // [32, 30] f32
    const float* bias = (const float*)d_in[2];   // [32] f32
    float*       out  = (float*)d_out;           // [16, 32] f32

    unsigned* pool = (unsigned*)d_ws;                          // [16,30] @ offset 0
    float*    tcap = (float*)((char*)d_ws + 2048);             // [16,4096] 256 KB

    hipLaunchKernelGGL(init_pool_kernel, dim3(1), dim3(512), 0, stream, pool);
    hipLaunchKernelGGL(knn_bound_kernel, dim3(BATCH * (NPTS / 64)), dim3(512),
                       0, stream, x, tcap);
    hipLaunchKernelGGL(knn_feat_kernel, dim3(BATCH * (NPTS / 64)), dim3(256),
                       0, stream, x, tcap, pool);
    hipLaunchKernelGGL(final_mm_kernel, dim3(1), dim3(512), 0, stream, pool, W, bias, out);
}